// Round 2
// baseline (1506.606 us; speedup 1.0000x reference)
//
#include <hip/hip_runtime.h>
#include <hip/hip_bf16.h>
#include <math.h>

#define NUM_EXPERTS 32
#define TOP_K 8
#define HIDDEN 1536
#define INTER 512

typedef __bf16 bf16_t;
typedef __bf16 bf16x8 __attribute__((ext_vector_type(8)));
typedef __bf16 bf16x4 __attribute__((ext_vector_type(4)));
typedef float f32x4 __attribute__((ext_vector_type(4)));

// meta layout (int indices)
#define M_COUNTS    0     // 32
#define M_OFFSETS   32    // 33
#define M_CURSORS   96    // 32
#define M_NUMTILES  128   // 1
#define M_TILE_E    256   // up to 640
#define M_TILE_M0   1024  // up to 640
#define M_TILE_ROWS 2048  // up to 640
#define META_BYTES  16384

__device__ __forceinline__ void gld16(void* lds, const void* gsrc) {
  __builtin_amdgcn_global_load_lds(
      (const __attribute__((address_space(1))) void*)gsrc,
      (__attribute__((address_space(3))) void*)lds, 16, 0, 0);
}

// ---------------- fp32 -> bf16 bulk convert ----------------
__global__ __launch_bounds__(256) void k_cvt(
    const float* __restrict__ src, bf16_t* __restrict__ dst)
{
  size_t i = ((size_t)blockIdx.x * 256 + threadIdx.x) * 4;
  f32x4 v = *(const f32x4*)(src + i);
  bf16x4 o;
  o[0] = (bf16_t)v[0]; o[1] = (bf16_t)v[1]; o[2] = (bf16_t)v[2]; o[3] = (bf16_t)v[3];
  *(bf16x4*)(dst + i) = o;
}

// ---------------- gate-weight transpose: gwT4[k>>2][e][k&3] = gw[e][k] ----------------
__global__ __launch_bounds__(256) void k_tgw(
    const float* __restrict__ gw, float* __restrict__ gwT4)
{
  int tid = blockIdx.x * 256 + threadIdx.x;   // 49152
  int e = tid / HIDDEN, k = tid % HIDDEN;
  gwT4[(k >> 2) * 128 + (e << 2) + (k & 3)] = gw[tid];
}

// ---------------- router: fp32 logits -> top8 -> weights + counts; also writes x16 ----------------
__global__ __launch_bounds__(64) void k_router(
    const float* __restrict__ x, const float* __restrict__ gwT4,
    int* __restrict__ meta, int* __restrict__ topk_idx, float* __restrict__ topk_w,
    bf16_t* __restrict__ x16)
{
  int t = blockIdx.x;
  int lane = threadIdx.x;          // 64 lanes
  int e = lane & 31, part = lane >> 5;
  const float* xrow = x + (size_t)t * HIDDEN;
  const f32x4* xr = (const f32x4*)(xrow + part * 768);
  const f32x4* gr = (const f32x4*)(gwT4 + part * 192 * 128 + e * 4);
  float s = 0.f;
#pragma unroll 4
  for (int i = 0; i < 192; ++i) {
    f32x4 xv = xr[i];
    f32x4 gv = gr[i * 32];     // coalesced: lanes 0..31 read 512B contiguous
    s += xv[0] * gv[0] + xv[1] * gv[1] + xv[2] * gv[2] + xv[3] * gv[3];
  }
  s += __shfl_xor(s, 32);          // full dot; lanes 0..31 (and dup 32..63) hold logit[e]

  // fused x -> bf16 (x row is L1/L2 hot)
  {
    const f32x4* xv4 = (const f32x4*)(xrow + lane * 24);
    bf16_t* xo = x16 + (size_t)t * HIDDEN + lane * 24;
#pragma unroll
    for (int i = 0; i < 6; ++i) {
      f32x4 v = xv4[i];
      bf16x4 o;
      o[0] = (bf16_t)v[0]; o[1] = (bf16_t)v[1]; o[2] = (bf16_t)v[2]; o[3] = (bf16_t)v[3];
      *(bf16x4*)(xo + i * 4) = o;
    }
  }

  float logit = s, rem = s;
  float m0 = 0.f, wsum = 0.f, my_l = 0.f;
  int my_e = 0;
#pragma unroll
  for (int k = 0; k < TOP_K; ++k) {
    float mx = rem;
#pragma unroll
    for (int off = 32; off >= 1; off >>= 1) mx = fmaxf(mx, __shfl_xor(mx, off));
    unsigned long long bal = __ballot(rem == mx);
    int src = __ffsll(bal) - 1;    // lowest lane -> lowest expert idx on ties
    int ex = src & 31;
    float lv = __shfl(logit, ex);
    if (k == 0) m0 = mx;
    wsum += __expf(lv - m0);
    if (lane == k) { my_e = ex; my_l = lv; }
    if ((lane & 31) == ex) rem = -1e30f;
  }
  if (lane < TOP_K) {
    topk_idx[t * TOP_K + lane] = my_e;
    topk_w[t * TOP_K + lane] = __expf(my_l - m0) / wsum;
    atomicAdd(&meta[M_COUNTS + my_e], 1);
  }
}

// ---------------- prefix sum + tile descriptors (tiny, 1 thread) ----------------
__global__ void k_scan(int* __restrict__ meta)
{
  if (threadIdx.x != 0 || blockIdx.x != 0) return;
  int off = 0, nt = 0;
  for (int e = 0; e < NUM_EXPERTS; ++e) {
    int n = meta[M_COUNTS + e];
    meta[M_OFFSETS + e] = off;
    meta[M_CURSORS + e] = off;
    int tn = (n + 127) >> 7;
    for (int i = 0; i < tn; ++i) {
      meta[M_TILE_E + nt] = e;
      meta[M_TILE_M0 + nt] = off + i * 128;
      meta[M_TILE_ROWS + nt] = min(128, n - i * 128);
      ++nt;
    }
    off += n;
  }
  meta[M_OFFSETS + NUM_EXPERTS] = off;
  meta[M_NUMTILES] = nt;
}

// ---------------- scatter pairs into expert-sorted order ----------------
// pair_pos[t*8+k] = position of that pair in expert-sorted order (for combine gather)
__global__ __launch_bounds__(256) void k_scatter(
    const int* __restrict__ topk_idx,
    int* __restrict__ meta, int* __restrict__ pair_token, int* __restrict__ pair_pos)
{
  int i = blockIdx.x * 256 + threadIdx.x;   // 0..T*8-1
  int e = topk_idx[i];
  int pos = atomicAdd(&meta[M_CURSORS + e], 1);
  pair_token[pos] = i >> 3;
  pair_pos[i] = pos;
}

// ---------------- GEMM1: act = silu(x@Wg^T) * (x@Wu^T), gathered rows ----------------
// C tile: 128 pair-rows x 256 cols (128 g + 128 u) -> per-lane silu fuse.
// Waves 2x2: each wave 64 rows x (64 g-cols + 64 u-cols) -> 12 frag reads / 32 MFMA per ks
// (was 2x16 frags: 18 reads / 32 MFMA). LDS read traffic per block -33%.
// Grid: 544*4 blocks, XCD-swizzled so a tile's 4 n-blocks share an XCD (x-slab L2 reuse).
// LDS: As[128][64], Bs[256][64] bf16, 16B-chunk XOR swizzle (chunk c of row r at c^(r&7)).
__global__ __launch_bounds__(256, 3) void k_gemm1(
    const bf16_t* __restrict__ x, const bf16_t* __restrict__ w13,
    const int* __restrict__ meta, const int* __restrict__ pair_token,
    bf16_t* __restrict__ act)
{
  int bid = blockIdx.x;
  int xcd = bid & 7, r2 = bid >> 3;
  int nb = r2 & 3, tile = xcd + 8 * (r2 >> 2);
  if (tile >= meta[M_NUMTILES]) return;
  int e    = meta[M_TILE_E + tile];
  int m0   = meta[M_TILE_M0 + tile];
  int rows = meta[M_TILE_ROWS + tile];
  int n0g  = nb * 128;

  __shared__ __align__(16) char smem[49152];
  char* As = smem;           // [128][64] bf16 swizzled
  char* Bs = smem + 16384;   // [256][64]

  int tid = threadIdx.x;
  int lane = tid & 63, w = tid >> 6;
  int wr = w >> 1, wc = w & 1;       // 2x2 wave grid
  int cd = lane & 7;                 // chunk this lane deposits (dest = base + lane*16)
  int lrow = w * 8 + (lane >> 3);    // + i*32 -> row

  const bf16_t* a_src[4];
  const bf16_t* b_src[8];
#pragma unroll
  for (int i = 0; i < 4; ++i) {
    int r = i * 32 + lrow;
    int rr = (r < rows) ? r : 0;               // clamp ragged rows to a valid token
    int tok = pair_token[m0 + rr];
    int cg = cd ^ (r & 7);                     // source chunk for swizzled store
    a_src[i] = x + (size_t)tok * HIDDEN + cg * 8;
  }
#pragma unroll
  for (int i = 0; i < 8; ++i) {
    int r = i * 32 + lrow;                     // 0..255
    int cg = cd ^ (r & 7);
    int gr = (r < 128) ? (n0g + r) : (512 + n0g + (r - 128));
    b_src[i] = w13 + (size_t)e * (2 * INTER) * HIDDEN + (size_t)gr * HIDDEN + cg * 8;
  }
  unsigned lds_off = w * 1024 + lane * 16;     // wave-contiguous (global_load_lds semantics)

  f32x4 acc[4][8] = {};
  int q = lane >> 4, cl = lane & 15;
  // A frag rows: wr*64 + mi*16 + cl ; B frag rows: g: wc*64 + ni*16 + cl, u: 128 + same
  int abase = (wr * 64 + cl) * 128;
  int bbase_g = (wc * 64 + cl) * 128;
  int bbase_u = (128 + wc * 64 + cl) * 128;

  for (int k0 = 0; k0 < HIDDEN; k0 += 64) {
#pragma unroll
    for (int i = 0; i < 4; ++i) gld16(As + i * 4096 + lds_off, a_src[i] + k0);
#pragma unroll
    for (int i = 0; i < 8; ++i) gld16(Bs + i * 4096 + lds_off, b_src[i] + k0);
    __syncthreads();
#pragma unroll
    for (int ks = 0; ks < 2; ++ks) {
      int csw = ((ks * 4 + q) ^ (lane & 7)) * 16;   // un-swizzle: frag rows have row&7 == lane&7
      bf16x8 a0 = *(const bf16x8*)(As + abase + 0 * 2048 + csw);
      bf16x8 a1 = *(const bf16x8*)(As + abase + 1 * 2048 + csw);
      bf16x8 a2 = *(const bf16x8*)(As + abase + 2 * 2048 + csw);
      bf16x8 a3 = *(const bf16x8*)(As + abase + 3 * 2048 + csw);
#pragma unroll
      for (int ni = 0; ni < 4; ++ni) {
        bf16x8 bg = *(const bf16x8*)(Bs + bbase_g + ni * 2048 + csw);
        acc[0][ni] = __builtin_amdgcn_mfma_f32_16x16x32_bf16(a0, bg, acc[0][ni], 0, 0, 0);
        acc[1][ni] = __builtin_amdgcn_mfma_f32_16x16x32_bf16(a1, bg, acc[1][ni], 0, 0, 0);
        acc[2][ni] = __builtin_amdgcn_mfma_f32_16x16x32_bf16(a2, bg, acc[2][ni], 0, 0, 0);
        acc[3][ni] = __builtin_amdgcn_mfma_f32_16x16x32_bf16(a3, bg, acc[3][ni], 0, 0, 0);
        bf16x8 bu = *(const bf16x8*)(Bs + bbase_u + ni * 2048 + csw);
        acc[0][ni + 4] = __builtin_amdgcn_mfma_f32_16x16x32_bf16(a0, bu, acc[0][ni + 4], 0, 0, 0);
        acc[1][ni + 4] = __builtin_amdgcn_mfma_f32_16x16x32_bf16(a1, bu, acc[1][ni + 4], 0, 0, 0);
        acc[2][ni + 4] = __builtin_amdgcn_mfma_f32_16x16x32_bf16(a2, bu, acc[2][ni + 4], 0, 0, 0);
        acc[3][ni + 4] = __builtin_amdgcn_mfma_f32_16x16x32_bf16(a3, bu, acc[3][ni + 4], 0, 0, 0);
      }
    }
    __syncthreads();
  }

  // epilogue: act = silu(g)*u ; g = acc[mi][0..3], u = acc[mi][4..7] -> same lane, per-lane math
#pragma unroll
  for (int mi = 0; mi < 4; ++mi) {
#pragma unroll
    for (int reg = 0; reg < 4; ++reg) {
      int row = wr * 64 + mi * 16 + q * 4 + reg;   // C/D: row=(lane>>4)*4+reg, col=lane&15
      if (row < rows) {
        bf16_t* obase = act + (size_t)(m0 + row) * INTER + n0g + wc * 64 + cl;
#pragma unroll
        for (int ni = 0; ni < 4; ++ni) {
          float g = acc[mi][ni][reg];
          float u = acc[mi][ni + 4][reg];
          float a = (g / (1.f + __expf(-g))) * u;
          obase[ni * 16] = (bf16_t)a;
        }
      }
    }
  }
}

// ---------------- GEMM2: y = act @ w2^T partials (bf16, unreduced), column-pass n0base ----------------
// C tile: 128 pair-rows x 256 out-cols; waves 2x2 (64x128 each): 12 frag reads / 32 MFMA per ks.
// Grid 544*3 per pass, XCD-swizzled (act slab L2 reuse).
// No atomics: plain bf16 stores of per-pair partials; k_combine reduces the 8 partials per token.
__global__ __launch_bounds__(256, 3) void k_gemm2(
    const bf16_t* __restrict__ act, const bf16_t* __restrict__ w2,
    const int* __restrict__ meta, bf16_t* __restrict__ y, int n0base)
{
  int bid = blockIdx.x;
  int xcd = bid & 7, r2 = bid >> 3;
  int nb = r2 % 3, tile = xcd + 8 * (r2 / 3);
  if (tile >= meta[M_NUMTILES]) return;
  int e    = meta[M_TILE_E + tile];
  int m0   = meta[M_TILE_M0 + tile];
  int rows = meta[M_TILE_ROWS + tile];
  int n0l  = nb * 256;            // local col within this 768-col pass
  int n0   = n0base + n0l;        // absolute w2 output row

  __shared__ __align__(16) char smem[49152];
  char* As = smem;           // [128][64]
  char* Bs = smem + 16384;   // [256][64]

  int tid = threadIdx.x;
  int lane = tid & 63, w = tid >> 6;
  int wr = w >> 1, wc = w & 1;
  int cd = lane & 7;
  int lrow = w * 8 + (lane >> 3);

  const bf16_t* a_src[4];
  const bf16_t* b_src[8];
#pragma unroll
  for (int i = 0; i < 4; ++i) {
    int r = i * 32 + lrow;
    int rr = (r < rows) ? r : 0;
    int cg = cd ^ (r & 7);
    a_src[i] = act + (size_t)(m0 + rr) * INTER + cg * 8;
  }
#pragma unroll
  for (int i = 0; i < 8; ++i) {
    int r = i * 32 + lrow;
    int cg = cd ^ (r & 7);
    b_src[i] = w2 + (size_t)e * HIDDEN * INTER + (size_t)(n0 + r) * INTER + cg * 8;
  }
  unsigned lds_off = w * 1024 + lane * 16;

  f32x4 acc[4][8] = {};
  int q = lane >> 4, cl = lane & 15;
  int abase = (wr * 64 + cl) * 128;
  int bbase = (wc * 128 + cl) * 128;

  for (int k0 = 0; k0 < INTER; k0 += 64) {
#pragma unroll
    for (int i = 0; i < 4; ++i) gld16(As + i * 4096 + lds_off, a_src[i] + k0);
#pragma unroll
    for (int i = 0; i < 8; ++i) gld16(Bs + i * 4096 + lds_off, b_src[i] + k0);
    __syncthreads();
#pragma unroll
    for (int ks = 0; ks < 2; ++ks) {
      int csw = ((ks * 4 + q) ^ (lane & 7)) * 16;
      bf16x8 a0 = *(const bf16x8*)(As + abase + 0 * 2048 + csw);
      bf16x8 a1 = *(const bf16x8*)(As + abase + 1 * 2048 + csw);
      bf16x8 a2 = *(const bf16x8*)(As + abase + 2 * 2048 + csw);
      bf16x8 a3 = *(const bf16x8*)(As + abase + 3 * 2048 + csw);
#pragma unroll
      for (int ni = 0; ni < 8; ++ni) {
        bf16x8 b = *(const bf16x8*)(Bs + bbase + ni * 2048 + csw);
        acc[0][ni] = __builtin_amdgcn_mfma_f32_16x16x32_bf16(a0, b, acc[0][ni], 0, 0, 0);
        acc[1][ni] = __builtin_amdgcn_mfma_f32_16x16x32_bf16(a1, b, acc[1][ni], 0, 0, 0);
        acc[2][ni] = __builtin_amdgcn_mfma_f32_16x16x32_bf16(a2, b, acc[2][ni], 0, 0, 0);
        acc[3][ni] = __builtin_amdgcn_mfma_f32_16x16x32_bf16(a3, b, acc[3][ni], 0, 0, 0);
      }
    }
    __syncthreads();
  }

  // epilogue: plain bf16 partial stores (no atomics, no weight — combine applies it)
#pragma unroll
  for (int mi = 0; mi < 4; ++mi) {
#pragma unroll
    for (int reg = 0; reg < 4; ++reg) {
      int row = wr * 64 + mi * 16 + q * 4 + reg;
      if (row < rows) {
        bf16_t* obase = y + (size_t)(m0 + row) * 768 + n0l + wc * 128 + cl;
#pragma unroll
        for (int ni = 0; ni < 8; ++ni)
          obase[ni * 16] = (bf16_t)acc[mi][ni][reg];
      }
    }
  }
}

// ---------------- combine: out[t] = sum_k topk_w[t,k] * y[pair_pos[t,k]] ----------------
// One 8-col chunk per thread; T*96 threads per pass. Writes out exactly once (no memset needed).
__global__ __launch_bounds__(256) void k_combine(
    const bf16_t* __restrict__ y, const int* __restrict__ pair_pos,
    const float* __restrict__ topk_w, float* __restrict__ out, int colbase)
{
  int idx = blockIdx.x * 256 + threadIdx.x;   // 0 .. T*96-1
  int t = idx / 96, c = idx % 96;
  const int*   pp = pair_pos + t * 8;
  const float* tw = topk_w + t * 8;
  f32x4 sa = {}, sb = {};
#pragma unroll
  for (int k = 0; k < 8; ++k) {
    int pos = pp[k];
    float wgt = tw[k];
    bf16x8 v = *(const bf16x8*)(y + (size_t)pos * 768 + c * 8);
    sa[0] += wgt * (float)v[0]; sa[1] += wgt * (float)v[1];
    sa[2] += wgt * (float)v[2]; sa[3] += wgt * (float)v[3];
    sb[0] += wgt * (float)v[4]; sb[1] += wgt * (float)v[5];
    sb[2] += wgt * (float)v[6]; sb[3] += wgt * (float)v[7];
  }
  float* o = out + (size_t)t * HIDDEN + colbase + c * 8;
  *(f32x4*)o = sa;
  *(f32x4*)(o + 4) = sb;
}

extern "C" void kernel_launch(void* const* d_in, const int* in_sizes, int n_in,
                              void* d_out, int out_size, void* d_ws, size_t ws_size,
                              hipStream_t stream)
{
  const float* x   = (const float*)d_in[0];
  const float* gw  = (const float*)d_in[1];
  const float* w13 = (const float*)d_in[2];
  const float* w2  = (const float*)d_in[3];
  float* out = (float*)d_out;

  const int T = in_sizes[0] / HIDDEN;   // 8192
  const int P = T * TOP_K;              // 65536
  const size_t NX   = (size_t)T * HIDDEN;
  const size_t NW13 = (size_t)NUM_EXPERTS * 2 * INTER * HIDDEN;
  const size_t NW2  = (size_t)NUM_EXPERTS * HIDDEN * INTER;

  char* ws = (char*)d_ws;
  int*    meta        = (int*)ws;                              // 16 KB
  int*    topk_idx    = (int*)(ws + META_BYTES);               // P ints
  float*  topk_w      = (float*)(ws + META_BYTES + (size_t)P * 4);
  int*    pair_token  = (int*)(ws + META_BYTES + (size_t)P * 8);
  int*    pair_pos    = (int*)(ws + META_BYTES + (size_t)P * 12);
  float*  gwT4        = (float*)(ws + (1536u << 10));          // 192 KB
  // big buffers: w2_16 and act live through gemm2; x16/w13_16 die after gemm1,
  // so the y partial buffer (P*768*2 = 100.7 MB) aliases [x16, w13_16] (125.8 MB).
  size_t off = 2u << 20;
  bf16_t* w2_16  = (bf16_t*)(ws + off); off += NW2 * 2;        // 50.3 MB
  bf16_t* act    = (bf16_t*)(ws + off); off += (size_t)P * INTER * 2;  // 67.1 MB
  size_t y_off = off;
  bf16_t* x16    = (bf16_t*)(ws + off); off += NX * 2;         // 25.2 MB
  bf16_t* w13_16 = (bf16_t*)(ws + off);                        // 100.7 MB (ends ~245.3 MB)
  bf16_t* y      = (bf16_t*)(ws + y_off);                      // aliases x16+w13_16

  hipMemsetAsync(meta, 0, 32 * sizeof(int), stream);

  k_tgw<<<(HIDDEN * NUM_EXPERTS) / 256, 256, 0, stream>>>(gw, gwT4);
  k_cvt<<<NW13 / 1024, 256, 0, stream>>>(w13, w13_16);
  k_cvt<<<NW2 / 1024, 256, 0, stream>>>(w2, w2_16);

  k_router<<<T, 64, 0, stream>>>(x, gwT4, meta, topk_idx, topk_w, x16);
  k_scan<<<1, 64, 0, stream>>>(meta);
  k_scatter<<<P / 256, 256, 0, stream>>>(topk_idx, meta, pair_token, pair_pos);

  // 544 = 68*8 max ragged tiles; XCD-swizzled 1D grids
  k_gemm1<<<544 * 4, 256, 0, stream>>>(x16, w13_16, meta, pair_token, act);

  // gemm2 in two 768-col passes so y fits the dead x16/w13_16 region; combine after each
  k_gemm2<<<544 * 3, 256, 0, stream>>>(act, w2_16, meta, y, 0);
  k_combine<<<(T * 96) / 256, 256, 0, stream>>>(y, pair_pos, topk_w, out, 0);
  k_gemm2<<<544 * 3, 256, 0, stream>>>(act, w2_16, meta, y, 768);
  k_combine<<<(T * 96) / 256, 256, 0, stream>>>(y, pair_pos, topk_w, out, 768);
}

// Round 3
// 1186.795 us; speedup vs baseline: 1.2695x; 1.2695x over previous
//
#include <hip/hip_runtime.h>
#include <hip/hip_bf16.h>
#include <math.h>

#define NUM_EXPERTS 32
#define TOP_K 8
#define HIDDEN 1536
#define INTER 512

typedef __bf16 bf16_t;
typedef __bf16 bf16x8 __attribute__((ext_vector_type(8)));
typedef __bf16 bf16x4 __attribute__((ext_vector_type(4)));
typedef float f32x4 __attribute__((ext_vector_type(4)));

// meta layout (int indices)
#define M_COUNTS    0     // 32
#define M_OFFSETS   32    // 33
#define M_CURSORS   96    // 32
#define M_NUMTILES  128   // 1
#define M_TILE_E    256   // up to 640
#define M_TILE_M0   1024  // up to 640
#define M_TILE_ROWS 2048  // up to 640
#define META_BYTES  16384

__device__ __forceinline__ void gld16(void* lds, const void* gsrc) {
  __builtin_amdgcn_global_load_lds(
      (const __attribute__((address_space(1))) void*)gsrc,
      (__attribute__((address_space(3))) void*)lds, 16, 0, 0);
}

// ---------------- fp32 -> bf16 bulk convert ----------------
__global__ __launch_bounds__(256) void k_cvt(
    const float* __restrict__ src, bf16_t* __restrict__ dst)
{
  size_t i = ((size_t)blockIdx.x * 256 + threadIdx.x) * 4;
  f32x4 v = *(const f32x4*)(src + i);
  bf16x4 o;
  o[0] = (bf16_t)v[0]; o[1] = (bf16_t)v[1]; o[2] = (bf16_t)v[2]; o[3] = (bf16_t)v[3];
  *(bf16x4*)(dst + i) = o;
}

// ---------------- gate-weight transpose: gwT4[k>>2][e][k&3] = gw[e][k] ----------------
__global__ __launch_bounds__(256) void k_tgw(
    const float* __restrict__ gw, float* __restrict__ gwT4)
{
  int tid = blockIdx.x * 256 + threadIdx.x;   // 49152
  int e = tid / HIDDEN, k = tid % HIDDEN;
  gwT4[(k >> 2) * 128 + (e << 2) + (k & 3)] = gw[tid];
}

// ---------------- router: fp32 logits -> top8 -> weights + counts; also writes x16 ----------------
__global__ __launch_bounds__(64) void k_router(
    const float* __restrict__ x, const float* __restrict__ gwT4,
    int* __restrict__ meta, int* __restrict__ topk_idx, float* __restrict__ topk_w,
    bf16_t* __restrict__ x16)
{
  int t = blockIdx.x;
  int lane = threadIdx.x;          // 64 lanes
  int e = lane & 31, part = lane >> 5;
  const float* xrow = x + (size_t)t * HIDDEN;
  const f32x4* xr = (const f32x4*)(xrow + part * 768);
  const f32x4* gr = (const f32x4*)(gwT4 + part * 192 * 128 + e * 4);
  float s = 0.f;
#pragma unroll 4
  for (int i = 0; i < 192; ++i) {
    f32x4 xv = xr[i];
    f32x4 gv = gr[i * 32];     // coalesced: lanes 0..31 read 512B contiguous
    s += xv[0] * gv[0] + xv[1] * gv[1] + xv[2] * gv[2] + xv[3] * gv[3];
  }
  s += __shfl_xor(s, 32);          // full dot; lanes 0..31 (and dup 32..63) hold logit[e]

  // fused x -> bf16 (x row is L1/L2 hot)
  {
    const f32x4* xv4 = (const f32x4*)(xrow + lane * 24);
    bf16_t* xo = x16 + (size_t)t * HIDDEN + lane * 24;
#pragma unroll
    for (int i = 0; i < 6; ++i) {
      f32x4 v = xv4[i];
      bf16x4 o;
      o[0] = (bf16_t)v[0]; o[1] = (bf16_t)v[1]; o[2] = (bf16_t)v[2]; o[3] = (bf16_t)v[3];
      *(bf16x4*)(xo + i * 4) = o;
    }
  }

  float logit = s, rem = s;
  float m0 = 0.f, wsum = 0.f, my_l = 0.f;
  int my_e = 0;
#pragma unroll
  for (int k = 0; k < TOP_K; ++k) {
    float mx = rem;
#pragma unroll
    for (int off = 32; off >= 1; off >>= 1) mx = fmaxf(mx, __shfl_xor(mx, off));
    unsigned long long bal = __ballot(rem == mx);
    int src = __ffsll(bal) - 1;    // lowest lane -> lowest expert idx on ties
    int ex = src & 31;
    float lv = __shfl(logit, ex);
    if (k == 0) m0 = mx;
    wsum += __expf(lv - m0);
    if (lane == k) { my_e = ex; my_l = lv; }
    if ((lane & 31) == ex) rem = -1e30f;
  }
  if (lane < TOP_K) {
    topk_idx[t * TOP_K + lane] = my_e;
    topk_w[t * TOP_K + lane] = __expf(my_l - m0) / wsum;
    atomicAdd(&meta[M_COUNTS + my_e], 1);
  }
}

// ---------------- prefix sum + tile descriptors (tiny, 1 thread) ----------------
__global__ void k_scan(int* __restrict__ meta)
{
  if (threadIdx.x != 0 || blockIdx.x != 0) return;
  int off = 0, nt = 0;
  for (int e = 0; e < NUM_EXPERTS; ++e) {
    int n = meta[M_COUNTS + e];
    meta[M_OFFSETS + e] = off;
    meta[M_CURSORS + e] = off;
    int tn = (n + 127) >> 7;
    for (int i = 0; i < tn; ++i) {
      meta[M_TILE_E + nt] = e;
      meta[M_TILE_M0 + nt] = off + i * 128;
      meta[M_TILE_ROWS + nt] = min(128, n - i * 128);
      ++nt;
    }
    off += n;
  }
  meta[M_OFFSETS + NUM_EXPERTS] = off;
  meta[M_NUMTILES] = nt;
}

// ---------------- scatter pairs into expert-sorted order ----------------
// pair_pos[t*8+k] = position of that pair in expert-sorted order (for combine gather)
__global__ __launch_bounds__(256) void k_scatter(
    const int* __restrict__ topk_idx,
    int* __restrict__ meta, int* __restrict__ pair_token, int* __restrict__ pair_pos)
{
  int i = blockIdx.x * 256 + threadIdx.x;   // 0..T*8-1
  int e = topk_idx[i];
  int pos = atomicAdd(&meta[M_CURSORS + e], 1);
  pair_token[pos] = i >> 3;
  pair_pos[i] = pos;
}

// ---------------- GEMM1: act = silu(x@Wg^T) * (x@Wu^T), gathered rows ----------------
// C tile: 128 pair-rows x 256 cols (128 g + 128 u); wave w owns rows w*32..+31 (4x1 tiling,
// proven round-1 K-loop). XCD mapping: balanced CONTIGUOUS chunks of work per XCD
// (each XCD walks ~68 consecutive tiles => ~4-5 experts through its private L2, not all 32).
// Epilogue: LDS-transpose (pitch 272B) -> fully-coalesced 256B-per-quarter-wave bf16x8 stores
// (kills the ~5x partial-line write amplification seen as WRITE_SIZE 357MB vs 67MB logical).
__global__ __launch_bounds__(256, 3) void k_gemm1(
    const bf16_t* __restrict__ x, const bf16_t* __restrict__ w13,
    const int* __restrict__ meta, const int* __restrict__ pair_token,
    bf16_t* __restrict__ act)
{
  int numtiles = meta[M_NUMTILES];
  int xcd = blockIdx.x & 7, s = blockIdx.x >> 3;     // assumes bid -> XCD round-robin
  int chunk = (numtiles * 4 + 7) >> 3;               // works per XCD, balanced
  if (s >= chunk) return;
  int W = xcd * chunk + s;
  int tile = W >> 2, nb = W & 3;
  if (tile >= numtiles) return;
  int e    = meta[M_TILE_E + tile];
  int m0   = meta[M_TILE_M0 + tile];
  int rows = meta[M_TILE_ROWS + tile];
  int n0g  = nb * 128;

  __shared__ __align__(16) char smem[49152];
  char* As = smem;           // [128][64] bf16 swizzled
  char* Bs = smem + 16384;   // [256][64]

  int tid = threadIdx.x;
  int lane = tid & 63, w = tid >> 6;
  int cd = lane & 7;                 // chunk this lane deposits (dest = base + lane*16)
  int lrow = w * 8 + (lane >> 3);    // + i*32 -> row

  const bf16_t* a_src[4];
  const bf16_t* b_src[8];
#pragma unroll
  for (int i = 0; i < 4; ++i) {
    int r = i * 32 + lrow;
    int rr = (r < rows) ? r : 0;               // clamp ragged rows to a valid token
    int tok = pair_token[m0 + rr];
    int cg = cd ^ (r & 7);                     // source chunk for swizzled store
    a_src[i] = x + (size_t)tok * HIDDEN + cg * 8;
  }
#pragma unroll
  for (int i = 0; i < 8; ++i) {
    int r = i * 32 + lrow;                     // 0..255
    int cg = cd ^ (r & 7);
    int gr = (r < 128) ? (n0g + r) : (512 + n0g + (r - 128));
    b_src[i] = w13 + (size_t)e * (2 * INTER) * HIDDEN + (size_t)gr * HIDDEN + cg * 8;
  }
  unsigned lds_off = w * 1024 + lane * 16;     // wave-contiguous (global_load_lds semantics)

  f32x4 acc[2][16] = {};
  int q = lane >> 4, cl = lane & 15;
  int arow0 = (w * 32 + cl) * 128;
  int arow1 = (w * 32 + 16 + cl) * 128;

  for (int k0 = 0; k0 < HIDDEN; k0 += 64) {
#pragma unroll
    for (int i = 0; i < 4; ++i) gld16(As + i * 4096 + lds_off, a_src[i] + k0);
#pragma unroll
    for (int i = 0; i < 8; ++i) gld16(Bs + i * 4096 + lds_off, b_src[i] + k0);
    __syncthreads();
#pragma unroll
    for (int ks = 0; ks < 2; ++ks) {
      int csw = ((ks * 4 + q) ^ (lane & 7)) * 16;   // un-swizzle: frag rows have row&7 == lane&7
      bf16x8 a0 = *(const bf16x8*)(As + arow0 + csw);
      bf16x8 a1 = *(const bf16x8*)(As + arow1 + csw);
#pragma unroll
      for (int in = 0; in < 16; ++in) {
        bf16x8 b = *(const bf16x8*)(Bs + (in * 16 + cl) * 128 + csw);
        acc[0][in] = __builtin_amdgcn_mfma_f32_16x16x32_bf16(a0, b, acc[0][in], 0, 0, 0);
        acc[1][in] = __builtin_amdgcn_mfma_f32_16x16x32_bf16(a1, b, acc[1][in], 0, 0, 0);
      }
    }
    __syncthreads();
  }

  // epilogue: silu fuse -> LDS transpose (per-wave 32 rows x 128 cols, pitch 272B) ->
  // coalesced bf16x8 stores: each quarter-wave writes a full 256B row segment.
  char* tb = smem + w * 8704;       // 32 * 272 = 8704B per wave; 4*8704 = 34816 <= 49152
#pragma unroll
  for (int im = 0; im < 2; ++im) {
#pragma unroll
    for (int reg = 0; reg < 4; ++reg) {
      int r = im * 16 + q * 4 + reg;           // C/D: row=(lane>>4)*4+reg, col=in*16+cl
#pragma unroll
      for (int in = 0; in < 8; ++in) {
        float g = acc[im][in][reg];
        float u = acc[im][in + 8][reg];
        float a = (g / (1.f + __expf(-g))) * u;
        *(bf16_t*)(tb + r * 272 + (in * 16 + cl) * 2) = (bf16_t)a;
      }
    }
  }
  // DS ops from one wave execute in order; lgkmcnt before register use is compiler-inserted.
#pragma unroll
  for (int i = 0; i < 8; ++i) {
    int r = (lane >> 4) + i * 4;               // 0..31
    bf16x8 v = *(const bf16x8*)(tb + r * 272 + (lane & 15) * 16);
    int row = w * 32 + r;
    if (row < rows)
      *(bf16x8*)(act + (size_t)(m0 + row) * INTER + n0g + (lane & 15) * 8) = v;
  }
}

// ---------------- GEMM2: y = act @ w2^T partials (bf16, unreduced), column-pass n0base ----------------
// C tile: 128 pair-rows x 256 out-cols; round-1 4x1 wave tiling. Chunked XCD mapping,
// LDS-transpose epilogue (pitch 528B, two 16-row phases): half-wave writes 512B contiguous.
__global__ __launch_bounds__(256, 3) void k_gemm2(
    const bf16_t* __restrict__ act, const bf16_t* __restrict__ w2,
    const int* __restrict__ meta, bf16_t* __restrict__ y, int n0base)
{
  int numtiles = meta[M_NUMTILES];
  int xcd = blockIdx.x & 7, s = blockIdx.x >> 3;
  int chunk = (numtiles * 3 + 7) >> 3;
  if (s >= chunk) return;
  int W = xcd * chunk + s;
  int tile = W / 3, nb = W - tile * 3;
  if (tile >= numtiles) return;
  int e    = meta[M_TILE_E + tile];
  int m0   = meta[M_TILE_M0 + tile];
  int rows = meta[M_TILE_ROWS + tile];
  int n0l  = nb * 256;            // local col within this 768-col pass
  int n0   = n0base + n0l;        // absolute w2 output row

  __shared__ __align__(16) char smem[49152];
  char* As = smem;           // [128][64]
  char* Bs = smem + 16384;   // [256][64]

  int tid = threadIdx.x;
  int lane = tid & 63, w = tid >> 6;
  int cd = lane & 7;
  int lrow = w * 8 + (lane >> 3);

  const bf16_t* a_src[4];
  const bf16_t* b_src[8];
#pragma unroll
  for (int i = 0; i < 4; ++i) {
    int r = i * 32 + lrow;
    int rr = (r < rows) ? r : 0;
    int cg = cd ^ (r & 7);
    a_src[i] = act + (size_t)(m0 + rr) * INTER + cg * 8;
  }
#pragma unroll
  for (int i = 0; i < 8; ++i) {
    int r = i * 32 + lrow;
    int cg = cd ^ (r & 7);
    b_src[i] = w2 + (size_t)e * HIDDEN * INTER + (size_t)(n0 + r) * INTER + cg * 8;
  }
  unsigned lds_off = w * 1024 + lane * 16;

  f32x4 acc[2][16] = {};
  int q = lane >> 4, cl = lane & 15;
  int arow0 = (w * 32 + cl) * 128;
  int arow1 = (w * 32 + 16 + cl) * 128;

  for (int k0 = 0; k0 < INTER; k0 += 64) {
#pragma unroll
    for (int i = 0; i < 4; ++i) gld16(As + i * 4096 + lds_off, a_src[i] + k0);
#pragma unroll
    for (int i = 0; i < 8; ++i) gld16(Bs + i * 4096 + lds_off, b_src[i] + k0);
    __syncthreads();
#pragma unroll
    for (int ks = 0; ks < 2; ++ks) {
      int csw = ((ks * 4 + q) ^ (lane & 7)) * 16;
      bf16x8 a0 = *(const bf16x8*)(As + arow0 + csw);
      bf16x8 a1 = *(const bf16x8*)(As + arow1 + csw);
#pragma unroll
      for (int in = 0; in < 16; ++in) {
        bf16x8 b = *(const bf16x8*)(Bs + (in * 16 + cl) * 128 + csw);
        acc[0][in] = __builtin_amdgcn_mfma_f32_16x16x32_bf16(a0, b, acc[0][in], 0, 0, 0);
        acc[1][in] = __builtin_amdgcn_mfma_f32_16x16x32_bf16(a1, b, acc[1][in], 0, 0, 0);
      }
    }
    __syncthreads();
  }

  // epilogue: LDS transpose, two 16-row phases (per-wave 16 rows x 256 cols, pitch 528B)
  char* tb = smem + w * 8448;       // 16 * 528 = 8448B per wave; 4*8448 = 33792 <= 49152
#pragma unroll
  for (int im = 0; im < 2; ++im) {
#pragma unroll
    for (int reg = 0; reg < 4; ++reg) {
      int r = q * 4 + reg;                     // 0..15
#pragma unroll
      for (int in = 0; in < 16; ++in)
        *(bf16_t*)(tb + r * 528 + (in * 16 + cl) * 2) = (bf16_t)acc[im][in][reg];
    }
    // per-wave in-order DS guarantees write->read; lgkmcnt handled by compiler
#pragma unroll
    for (int i = 0; i < 8; ++i) {
      int r = (lane >> 5) + i * 2;             // 0..15
      bf16x8 v = *(const bf16x8*)(tb + r * 528 + (lane & 31) * 16);
      int row = w * 32 + im * 16 + r;
      if (row < rows)
        *(bf16x8*)(y + (size_t)(m0 + row) * 768 + n0l + (lane & 31) * 8) = v;
    }
  }
}

// ---------------- combine: out[t] = sum_k topk_w[t,k] * y[pair_pos[t,k]] ----------------
// One 8-col chunk per thread; T*96 threads per pass. Writes out exactly once (no memset needed).
__global__ __launch_bounds__(256) void k_combine(
    const bf16_t* __restrict__ y, const int* __restrict__ pair_pos,
    const float* __restrict__ topk_w, float* __restrict__ out, int colbase)
{
  int idx = blockIdx.x * 256 + threadIdx.x;   // 0 .. T*96-1
  int t = idx / 96, c = idx % 96;
  const int*   pp = pair_pos + t * 8;
  const float* tw = topk_w + t * 8;
  f32x4 sa = {}, sb = {};
#pragma unroll
  for (int k = 0; k < 8; ++k) {
    int pos = pp[k];
    float wgt = tw[k];
    bf16x8 v = *(const bf16x8*)(y + (size_t)pos * 768 + c * 8);
    sa[0] += wgt * (float)v[0]; sa[1] += wgt * (float)v[1];
    sa[2] += wgt * (float)v[2]; sa[3] += wgt * (float)v[3];
    sb[0] += wgt * (float)v[4]; sb[1] += wgt * (float)v[5];
    sb[2] += wgt * (float)v[6]; sb[3] += wgt * (float)v[7];
  }
  float* o = out + (size_t)t * HIDDEN + colbase + c * 8;
  *(f32x4*)o = sa;
  *(f32x4*)(o + 4) = sb;
}

extern "C" void kernel_launch(void* const* d_in, const int* in_sizes, int n_in,
                              void* d_out, int out_size, void* d_ws, size_t ws_size,
                              hipStream_t stream)
{
  const float* x   = (const float*)d_in[0];
  const float* gw  = (const float*)d_in[1];
  const float* w13 = (const float*)d_in[2];
  const float* w2  = (const float*)d_in[3];
  float* out = (float*)d_out;

  const int T = in_sizes[0] / HIDDEN;   // 8192
  const int P = T * TOP_K;              // 65536
  const size_t NX   = (size_t)T * HIDDEN;
  const size_t NW13 = (size_t)NUM_EXPERTS * 2 * INTER * HIDDEN;
  const size_t NW2  = (size_t)NUM_EXPERTS * HIDDEN * INTER;

  char* ws = (char*)d_ws;
  int*    meta        = (int*)ws;                              // 16 KB
  int*    topk_idx    = (int*)(ws + META_BYTES);               // P ints
  float*  topk_w      = (float*)(ws + META_BYTES + (size_t)P * 4);
  int*    pair_token  = (int*)(ws + META_BYTES + (size_t)P * 8);
  int*    pair_pos    = (int*)(ws + META_BYTES + (size_t)P * 12);
  float*  gwT4        = (float*)(ws + (1536u << 10));          // 192 KB
  // big buffers: w2_16 and act live through gemm2; x16/w13_16 die after gemm1,
  // so the y partial buffer (P*768*2 = 100.7 MB) aliases [x16, w13_16] (125.8 MB).
  size_t off = 2u << 20;
  bf16_t* w2_16  = (bf16_t*)(ws + off); off += NW2 * 2;        // 50.3 MB
  bf16_t* act    = (bf16_t*)(ws + off); off += (size_t)P * INTER * 2;  // 67.1 MB
  size_t y_off = off;
  bf16_t* x16    = (bf16_t*)(ws + off); off += NX * 2;         // 25.2 MB
  bf16_t* w13_16 = (bf16_t*)(ws + off);                        // 100.7 MB (ends ~245.3 MB)
  bf16_t* y      = (bf16_t*)(ws + y_off);                      // aliases x16+w13_16

  hipMemsetAsync(meta, 0, 32 * sizeof(int), stream);

  k_tgw<<<(HIDDEN * NUM_EXPERTS) / 256, 256, 0, stream>>>(gw, gwT4);
  k_cvt<<<NW13 / 1024, 256, 0, stream>>>(w13, w13_16);
  k_cvt<<<NW2 / 1024, 256, 0, stream>>>(w2, w2_16);

  k_router<<<T, 64, 0, stream>>>(x, gwT4, meta, topk_idx, topk_w, x16);
  k_scan<<<1, 64, 0, stream>>>(meta);
  k_scatter<<<P / 256, 256, 0, stream>>>(topk_idx, meta, pair_token, pair_pos);

  // 544*4 / 544*3 block budgets; per-XCD contiguous work chunks computed from numtiles
  k_gemm1<<<544 * 4, 256, 0, stream>>>(x16, w13_16, meta, pair_token, act);

  // gemm2 in two 768-col passes so y fits the dead x16/w13_16 region; combine after each
  k_gemm2<<<544 * 3, 256, 0, stream>>>(act, w2_16, meta, y, 0);
  k_combine<<<(T * 96) / 256, 256, 0, stream>>>(y, pair_pos, topk_w, out, 0);
  k_gemm2<<<544 * 3, 256, 0, stream>>>(act, w2_16, meta, y, 768);
  k_combine<<<(T * 96) / 256, 256, 0, stream>>>(y, pair_pos, topk_w, out, 768);
}

// Round 4
// 1096.736 us; speedup vs baseline: 1.3737x; 1.0821x over previous
//
#include <hip/hip_runtime.h>
#include <hip/hip_bf16.h>
#include <math.h>

#define NUM_EXPERTS 32
#define TOP_K 8
#define HIDDEN 1536
#define INTER 512

typedef __bf16 bf16_t;
typedef __bf16 bf16x8 __attribute__((ext_vector_type(8)));
typedef __bf16 bf16x4 __attribute__((ext_vector_type(4)));
typedef float f32x4 __attribute__((ext_vector_type(4)));

// meta layout (int indices)
#define M_COUNTS    0     // 32
#define M_OFFSETS   32    // 33
#define M_NUMTILES  128   // 1
#define M_TILE_E    256   // up to 640
#define M_TILE_M0   1024  // up to 640
#define M_TILE_ROWS 2048  // up to 640
#define META_BYTES  16384

__device__ __forceinline__ void gld16(void* lds, const void* gsrc) {
  __builtin_amdgcn_global_load_lds(
      (const __attribute__((address_space(1))) void*)gsrc,
      (__attribute__((address_space(3))) void*)lds, 16, 0, 0);
}

// ---------------- fp32 -> bf16 bulk convert (8 elems/thread, 16B stores) ----------------
__global__ __launch_bounds__(256) void k_cvt(
    const float* __restrict__ src, bf16_t* __restrict__ dst)
{
  size_t i = ((size_t)blockIdx.x * 256 + threadIdx.x) * 8;
  f32x4 a = *(const f32x4*)(src + i);
  f32x4 b = *(const f32x4*)(src + i + 4);
  bf16x8 o;
  o[0] = (bf16_t)a[0]; o[1] = (bf16_t)a[1]; o[2] = (bf16_t)a[2]; o[3] = (bf16_t)a[3];
  o[4] = (bf16_t)b[0]; o[5] = (bf16_t)b[1]; o[6] = (bf16_t)b[2]; o[7] = (bf16_t)b[3];
  *(bf16x8*)(dst + i) = o;
}

// ---------------- gate-weight transpose: gwT4[k>>2][e][k&3] = gw[e][k] ----------------
__global__ __launch_bounds__(256) void k_tgw(
    const float* __restrict__ gw, float* __restrict__ gwT4)
{
  int tid = blockIdx.x * 256 + threadIdx.x;   // 49152
  int e = tid / HIDDEN, k = tid % HIDDEN;
  gwT4[(k >> 2) * 128 + (e << 2) + (k & 3)] = gw[tid];
}

// ---------------- router: fp32 logits -> top8 -> weights; also writes x16. NO atomics. ----------------
__global__ __launch_bounds__(64) void k_router(
    const float* __restrict__ x, const float* __restrict__ gwT4,
    int* __restrict__ topk_idx, float* __restrict__ topk_w,
    bf16_t* __restrict__ x16)
{
  int t = blockIdx.x;
  int lane = threadIdx.x;          // 64 lanes
  int e = lane & 31, part = lane >> 5;
  const float* xrow = x + (size_t)t * HIDDEN;
  const f32x4* xr = (const f32x4*)(xrow + part * 768);
  const f32x4* gr = (const f32x4*)(gwT4 + part * 192 * 128 + e * 4);
  float s = 0.f;
#pragma unroll 4
  for (int i = 0; i < 192; ++i) {
    f32x4 xv = xr[i];
    f32x4 gv = gr[i * 32];     // coalesced: lanes 0..31 read 512B contiguous
    s += xv[0] * gv[0] + xv[1] * gv[1] + xv[2] * gv[2] + xv[3] * gv[3];
  }
  s += __shfl_xor(s, 32);          // full dot; lanes 0..31 (and dup 32..63) hold logit[e]

  // fused x -> bf16 (x row is L1/L2 hot)
  {
    const f32x4* xv4 = (const f32x4*)(xrow + lane * 24);
    bf16_t* xo = x16 + (size_t)t * HIDDEN + lane * 24;
#pragma unroll
    for (int i = 0; i < 6; ++i) {
      f32x4 v = xv4[i];
      bf16x4 o;
      o[0] = (bf16_t)v[0]; o[1] = (bf16_t)v[1]; o[2] = (bf16_t)v[2]; o[3] = (bf16_t)v[3];
      *(bf16x4*)(xo + i * 4) = o;
    }
  }

  float logit = s, rem = s;
  float m0 = 0.f, wsum = 0.f, my_l = 0.f;
  int my_e = 0;
#pragma unroll
  for (int k = 0; k < TOP_K; ++k) {
    float mx = rem;
#pragma unroll
    for (int off = 32; off >= 1; off >>= 1) mx = fmaxf(mx, __shfl_xor(mx, off));
    unsigned long long bal = __ballot(rem == mx);
    int src = __ffsll(bal) - 1;    // lowest lane -> lowest expert idx on ties
    int ex = src & 31;
    float lv = __shfl(logit, ex);
    if (k == 0) m0 = mx;
    wsum += __expf(lv - m0);
    if (lane == k) { my_e = ex; my_l = lv; }
    if ((lane & 31) == ex) rem = -1e30f;
  }
  if (lane < TOP_K) {
    topk_idx[t * TOP_K + lane] = my_e;
    topk_w[t * TOP_K + lane] = __expf(my_l - m0) / wsum;
  }
}

// ---------------- per-block expert histogram (LDS atomics only, plain global stores) ----------------
__global__ __launch_bounds__(1024) void k_hist(
    const int* __restrict__ topk_idx, int* __restrict__ hist)
{
  __shared__ int h[NUM_EXPERTS];
  int t = threadIdx.x;
  if (t < NUM_EXPERTS) h[t] = 0;
  __syncthreads();
  int e = topk_idx[(size_t)blockIdx.x * 1024 + t];
  atomicAdd(&h[e], 1);
  __syncthreads();
  if (t < NUM_EXPERTS) hist[blockIdx.x * NUM_EXPERTS + t] = h[t];
}

// ---------------- prefix sums: expert offsets, per-block bases, tile descriptors ----------------
__global__ void k_scan(int* __restrict__ meta, const int* __restrict__ hist,
                       int* __restrict__ base, int nhb)
{
  if (threadIdx.x != 0 || blockIdx.x != 0) return;
  int off = 0, nt = 0;
  for (int e = 0; e < NUM_EXPERTS; ++e) {
    int run = off;
    for (int b = 0; b < nhb; ++b) {
      base[b * NUM_EXPERTS + e] = run;
      run += hist[b * NUM_EXPERTS + e];
    }
    int n = run - off;
    meta[M_COUNTS + e] = n;
    meta[M_OFFSETS + e] = off;
    int tn = (n + 127) >> 7;
    for (int i = 0; i < tn; ++i) {
      meta[M_TILE_E + nt] = e;
      meta[M_TILE_M0 + nt] = off + i * 128;
      meta[M_TILE_ROWS + nt] = min(128, n - i * 128);
      ++nt;
    }
    off += n;
  }
  meta[M_OFFSETS + NUM_EXPERTS] = off;
  meta[M_NUMTILES] = nt;
}

// ---------------- scatter: pos = base[blk][e] + LDS-local rank. Zero global atomics. ----------------
__global__ __launch_bounds__(1024) void k_scatter(
    const int* __restrict__ topk_idx, const int* __restrict__ base,
    int* __restrict__ pair_token, int* __restrict__ pair_pos)
{
  __shared__ int h[NUM_EXPERTS];
  int t = threadIdx.x;
  if (t < NUM_EXPERTS) h[t] = 0;
  __syncthreads();
  int i = blockIdx.x * 1024 + t;
  int e = topk_idx[i];
  int r = atomicAdd(&h[e], 1);
  int pos = base[blockIdx.x * NUM_EXPERTS + e] + r;
  pair_token[pos] = i >> 3;
  pair_pos[i] = pos;
}

// ---------------- GEMM1: act = silu(x@Wg^T) * (x@Wu^T), gathered rows ----------------
// (unchanged from round 3: chunked-XCD mapping, swizzled gld_lds staging, LDS-transpose epilogue)
__global__ __launch_bounds__(256, 3) void k_gemm1(
    const bf16_t* __restrict__ x, const bf16_t* __restrict__ w13,
    const int* __restrict__ meta, const int* __restrict__ pair_token,
    bf16_t* __restrict__ act)
{
  int numtiles = meta[M_NUMTILES];
  int xcd = blockIdx.x & 7, s = blockIdx.x >> 3;
  int chunk = (numtiles * 4 + 7) >> 3;
  if (s >= chunk) return;
  int W = xcd * chunk + s;
  int tile = W >> 2, nb = W & 3;
  if (tile >= numtiles) return;
  int e    = meta[M_TILE_E + tile];
  int m0   = meta[M_TILE_M0 + tile];
  int rows = meta[M_TILE_ROWS + tile];
  int n0g  = nb * 128;

  __shared__ __align__(16) char smem[49152];
  char* As = smem;           // [128][64] bf16 swizzled
  char* Bs = smem + 16384;   // [256][64]

  int tid = threadIdx.x;
  int lane = tid & 63, w = tid >> 6;
  int cd = lane & 7;
  int lrow = w * 8 + (lane >> 3);

  const bf16_t* a_src[4];
  const bf16_t* b_src[8];
#pragma unroll
  for (int i = 0; i < 4; ++i) {
    int r = i * 32 + lrow;
    int rr = (r < rows) ? r : 0;
    int tok = pair_token[m0 + rr];
    int cg = cd ^ (r & 7);
    a_src[i] = x + (size_t)tok * HIDDEN + cg * 8;
  }
#pragma unroll
  for (int i = 0; i < 8; ++i) {
    int r = i * 32 + lrow;
    int cg = cd ^ (r & 7);
    int gr = (r < 128) ? (n0g + r) : (512 + n0g + (r - 128));
    b_src[i] = w13 + (size_t)e * (2 * INTER) * HIDDEN + (size_t)gr * HIDDEN + cg * 8;
  }
  unsigned lds_off = w * 1024 + lane * 16;

  f32x4 acc[2][16] = {};
  int q = lane >> 4, cl = lane & 15;
  int arow0 = (w * 32 + cl) * 128;
  int arow1 = (w * 32 + 16 + cl) * 128;

  for (int k0 = 0; k0 < HIDDEN; k0 += 64) {
#pragma unroll
    for (int i = 0; i < 4; ++i) gld16(As + i * 4096 + lds_off, a_src[i] + k0);
#pragma unroll
    for (int i = 0; i < 8; ++i) gld16(Bs + i * 4096 + lds_off, b_src[i] + k0);
    __syncthreads();
#pragma unroll
    for (int ks = 0; ks < 2; ++ks) {
      int csw = ((ks * 4 + q) ^ (lane & 7)) * 16;
      bf16x8 a0 = *(const bf16x8*)(As + arow0 + csw);
      bf16x8 a1 = *(const bf16x8*)(As + arow1 + csw);
#pragma unroll
      for (int in = 0; in < 16; ++in) {
        bf16x8 b = *(const bf16x8*)(Bs + (in * 16 + cl) * 128 + csw);
        acc[0][in] = __builtin_amdgcn_mfma_f32_16x16x32_bf16(a0, b, acc[0][in], 0, 0, 0);
        acc[1][in] = __builtin_amdgcn_mfma_f32_16x16x32_bf16(a1, b, acc[1][in], 0, 0, 0);
      }
    }
    __syncthreads();
  }

  char* tb = smem + w * 8704;
#pragma unroll
  for (int im = 0; im < 2; ++im) {
#pragma unroll
    for (int reg = 0; reg < 4; ++reg) {
      int r = im * 16 + q * 4 + reg;
#pragma unroll
      for (int in = 0; in < 8; ++in) {
        float g = acc[im][in][reg];
        float u = acc[im][in + 8][reg];
        float a = (g / (1.f + __expf(-g))) * u;
        *(bf16_t*)(tb + r * 272 + (in * 16 + cl) * 2) = (bf16_t)a;
      }
    }
  }
#pragma unroll
  for (int i = 0; i < 8; ++i) {
    int r = (lane >> 4) + i * 4;
    bf16x8 v = *(const bf16x8*)(tb + r * 272 + (lane & 15) * 16);
    int row = w * 32 + r;
    if (row < rows)
      *(bf16x8*)(act + (size_t)(m0 + row) * INTER + n0g + (lane & 15) * 8) = v;
  }
}

// ---------------- GEMM2: y = act @ w2^T partials (bf16, unreduced) ----------------
// NBp n-blocks per tile (3 for 2-pass / 6 for single-pass), ypitch = NBp*256.
__global__ __launch_bounds__(256, 3) void k_gemm2(
    const bf16_t* __restrict__ act, const bf16_t* __restrict__ w2,
    const int* __restrict__ meta, bf16_t* __restrict__ y,
    int n0base, int NBp, int ypitch)
{
  int numtiles = meta[M_NUMTILES];
  int xcd = blockIdx.x & 7, s = blockIdx.x >> 3;
  int chunk = (numtiles * NBp + 7) >> 3;
  if (s >= chunk) return;
  int W = xcd * chunk + s;
  int tile = W / NBp, nb = W - tile * NBp;
  if (tile >= numtiles) return;
  int e    = meta[M_TILE_E + tile];
  int m0   = meta[M_TILE_M0 + tile];
  int rows = meta[M_TILE_ROWS + tile];
  int n0l  = nb * 256;
  int n0   = n0base + n0l;

  __shared__ __align__(16) char smem[49152];
  char* As = smem;           // [128][64]
  char* Bs = smem + 16384;   // [256][64]

  int tid = threadIdx.x;
  int lane = tid & 63, w = tid >> 6;
  int cd = lane & 7;
  int lrow = w * 8 + (lane >> 3);

  const bf16_t* a_src[4];
  const bf16_t* b_src[8];
#pragma unroll
  for (int i = 0; i < 4; ++i) {
    int r = i * 32 + lrow;
    int rr = (r < rows) ? r : 0;
    int cg = cd ^ (r & 7);
    a_src[i] = act + (size_t)(m0 + rr) * INTER + cg * 8;
  }
#pragma unroll
  for (int i = 0; i < 8; ++i) {
    int r = i * 32 + lrow;
    int cg = cd ^ (r & 7);
    b_src[i] = w2 + (size_t)e * HIDDEN * INTER + (size_t)(n0 + r) * INTER + cg * 8;
  }
  unsigned lds_off = w * 1024 + lane * 16;

  f32x4 acc[2][16] = {};
  int q = lane >> 4, cl = lane & 15;
  int arow0 = (w * 32 + cl) * 128;
  int arow1 = (w * 32 + 16 + cl) * 128;

  for (int k0 = 0; k0 < INTER; k0 += 64) {
#pragma unroll
    for (int i = 0; i < 4; ++i) gld16(As + i * 4096 + lds_off, a_src[i] + k0);
#pragma unroll
    for (int i = 0; i < 8; ++i) gld16(Bs + i * 4096 + lds_off, b_src[i] + k0);
    __syncthreads();
#pragma unroll
    for (int ks = 0; ks < 2; ++ks) {
      int csw = ((ks * 4 + q) ^ (lane & 7)) * 16;
      bf16x8 a0 = *(const bf16x8*)(As + arow0 + csw);
      bf16x8 a1 = *(const bf16x8*)(As + arow1 + csw);
#pragma unroll
      for (int in = 0; in < 16; ++in) {
        bf16x8 b = *(const bf16x8*)(Bs + (in * 16 + cl) * 128 + csw);
        acc[0][in] = __builtin_amdgcn_mfma_f32_16x16x32_bf16(a0, b, acc[0][in], 0, 0, 0);
        acc[1][in] = __builtin_amdgcn_mfma_f32_16x16x32_bf16(a1, b, acc[1][in], 0, 0, 0);
      }
    }
    __syncthreads();
  }

  // epilogue: LDS transpose, two 16-row phases (pitch 528B): coalesced 512B half-wave stores
  char* tb = smem + w * 8448;
#pragma unroll
  for (int im = 0; im < 2; ++im) {
#pragma unroll
    for (int reg = 0; reg < 4; ++reg) {
      int r = q * 4 + reg;
#pragma unroll
      for (int in = 0; in < 16; ++in)
        *(bf16_t*)(tb + r * 528 + (in * 16 + cl) * 2) = (bf16_t)acc[im][in][reg];
    }
#pragma unroll
    for (int i = 0; i < 8; ++i) {
      int r = (lane >> 5) + i * 2;
      bf16x8 v = *(const bf16x8*)(tb + r * 528 + (lane & 31) * 16);
      int row = w * 32 + im * 16 + r;
      if (row < rows)
        *(bf16x8*)(y + (size_t)(m0 + row) * ypitch + n0l + (lane & 31) * 8) = v;
    }
  }
}

// ---------------- combine: out[t][colbase+c*8..] = sum_k topk_w[t,k] * y[pos_k][c*8..] ----------------
__global__ __launch_bounds__(256) void k_combine(
    const bf16_t* __restrict__ y, const int* __restrict__ pair_pos,
    const float* __restrict__ topk_w, float* __restrict__ out,
    int colbase, int CP)
{
  int idx = blockIdx.x * 256 + threadIdx.x;
  int cpg = CP >> 3;                 // col-groups per token (96 or 192)
  int t = idx / cpg, c = idx % cpg;
  const int*   pp = pair_pos + t * 8;
  const float* tw = topk_w + t * 8;
  f32x4 sa = {}, sb = {};
#pragma unroll
  for (int k = 0; k < 8; ++k) {
    int pos = pp[k];
    float wgt = tw[k];
    bf16x8 v = *(const bf16x8*)(y + (size_t)pos * CP + c * 8);
    sa[0] += wgt * (float)v[0]; sa[1] += wgt * (float)v[1];
    sa[2] += wgt * (float)v[2]; sa[3] += wgt * (float)v[3];
    sb[0] += wgt * (float)v[4]; sb[1] += wgt * (float)v[5];
    sb[2] += wgt * (float)v[6]; sb[3] += wgt * (float)v[7];
  }
  float* o = out + (size_t)t * HIDDEN + colbase + c * 8;
  *(f32x4*)o = sa;
  *(f32x4*)(o + 4) = sb;
}

extern "C" void kernel_launch(void* const* d_in, const int* in_sizes, int n_in,
                              void* d_out, int out_size, void* d_ws, size_t ws_size,
                              hipStream_t stream)
{
  const float* x   = (const float*)d_in[0];
  const float* gw  = (const float*)d_in[1];
  const float* w13 = (const float*)d_in[2];
  const float* w2  = (const float*)d_in[3];
  float* out = (float*)d_out;

  const int T = in_sizes[0] / HIDDEN;   // 8192
  const int P = T * TOP_K;              // 65536
  const int HB = P / 1024;              // hist blocks (64)
  const int NTMAX = (P >> 7) + NUM_EXPERTS;  // 544
  const size_t NX   = (size_t)T * HIDDEN;
  const size_t NW13 = (size_t)NUM_EXPERTS * 2 * INTER * HIDDEN;
  const size_t NW2  = (size_t)NUM_EXPERTS * HIDDEN * INTER;

  char* ws = (char*)d_ws;
  int*    meta        = (int*)ws;                              // 16 KB
  int*    topk_idx    = (int*)(ws + META_BYTES);               // P ints
  float*  topk_w      = (float*)(ws + META_BYTES + (size_t)P * 4);
  int*    pair_token  = (int*)(ws + META_BYTES + (size_t)P * 8);
  int*    pair_pos    = (int*)(ws + META_BYTES + (size_t)P * 12);
  int*    hist        = (int*)(ws + META_BYTES + (size_t)P * 16);            // HB*32 ints
  int*    base        = hist + HB * NUM_EXPERTS;                             // HB*32 ints
  float*  gwT4        = (float*)(ws + (1536u << 10));          // 192 KB
  // big buffers: w2_16 and act live through gemm2; x16/w13_16 die after gemm1.
  // y aliases [x16, w13_16]; single-pass (ypitch 1536, 201MB) only if ws_size allows.
  size_t off = 2u << 20;
  bf16_t* w2_16  = (bf16_t*)(ws + off); off += NW2 * 2;        // 50.3 MB
  bf16_t* act    = (bf16_t*)(ws + off); off += (size_t)P * INTER * 2;  // 67.1 MB
  size_t y_off = off;
  bf16_t* x16    = (bf16_t*)(ws + off); off += NX * 2;         // 25.2 MB
  bf16_t* w13_16 = (bf16_t*)(ws + off);                        // 100.7 MB
  bf16_t* y      = (bf16_t*)(ws + y_off);                      // aliases x16+w13_16

  bool onepass = ws_size >= y_off + (size_t)P * HIDDEN * 2 + (4u << 20);

  k_tgw<<<(HIDDEN * NUM_EXPERTS) / 256, 256, 0, stream>>>(gw, gwT4);
  k_cvt<<<NW13 / 2048, 256, 0, stream>>>(w13, w13_16);
  k_cvt<<<NW2 / 2048, 256, 0, stream>>>(w2, w2_16);

  k_router<<<T, 64, 0, stream>>>(x, gwT4, topk_idx, topk_w, x16);
  k_hist<<<HB, 1024, 0, stream>>>(topk_idx, hist);
  k_scan<<<1, 64, 0, stream>>>(meta, hist, base, HB);
  k_scatter<<<HB, 1024, 0, stream>>>(topk_idx, base, pair_token, pair_pos);

  k_gemm1<<<NTMAX * 4, 256, 0, stream>>>(x16, w13_16, meta, pair_token, act);

  if (onepass) {
    k_gemm2<<<NTMAX * 6, 256, 0, stream>>>(act, w2_16, meta, y, 0, 6, 1536);
    k_combine<<<(T * 192) / 256, 256, 0, stream>>>(y, pair_pos, topk_w, out, 0, 1536);
  } else {
    k_gemm2<<<NTMAX * 3, 256, 0, stream>>>(act, w2_16, meta, y, 0, 3, 768);
    k_combine<<<(T * 96) / 256, 256, 0, stream>>>(y, pair_pos, topk_w, out, 0, 768);
    k_gemm2<<<NTMAX * 3, 256, 0, stream>>>(act, w2_16, meta, y, 768, 3, 768);
    k_combine<<<(T * 96) / 256, 256, 0, stream>>>(y, pair_pos, topk_w, out, 768, 768);
  }
}